// Round 1
// baseline (91.228 us; speedup 1.0000x reference)
//
#include <hip/hip_runtime.h>

// VariationalFFNGradientEngine — algebraically reduced via orthogonality of
// E = expm(phi . G) (G antisymmetric):
//   v_n   = E_n^T mu_n
//   Minv_n = E_n^T diag(1/(sq_n+eps)) E_n          (exact (Sigma_t+eps I)^{-1} core)
//   t_ij  = Minv_j (v_i - v_j),  kl_ij = 0.5 w.t   (rotated frame)
//   grad_mu_i = self + E_i [ LAM*a + (LAM/KAPPA)(c - s*a) ]
//     a = sum_j beta t, c = sum_j beta*kl*t, s = sum_j beta*kl

#define BB 8
#define NN 128
#define KK 16
#define ALPHA 0.01f
#define LAM 1.0f
#define KAPPA 1.0f
#define EPSV 1e-6f
#define TI 4

__global__ __launch_bounds__(256) void vffn_precompute(
    const float* __restrict__ mu_q, const float* __restrict__ sigma_q,
    const float* __restrict__ sigma_p, const float* __restrict__ phi,
    const float* __restrict__ gen,
    float* __restrict__ E_ws, float* __restrict__ Minv_ws,
    float* __restrict__ v_ws, float* __restrict__ grad_sigma)
{
    const int bn  = blockIdx.x;      // 0..1023 = b*128+n
    const int tid = threadIdx.x;     // 0..255 = r*16+c
    const int r = tid >> 4, c = tid & 15;

    __shared__ float X[256];
    __shared__ float A[256];
    __shared__ float red[4];
    __shared__ float dinv_s[16];

    const float p0 = phi[bn*3+0], p1 = phi[bn*3+1], p2 = phi[bn*3+2];
    float x = p0*gen[tid] + p1*gen[256+tid] + p2*gen[512+tid];

    // Frobenius norm^2 (bounds spectral norm) for scaling-and-squaring
    float ss = x*x;
    #pragma unroll
    for (int off = 32; off > 0; off >>= 1) ss += __shfl_down(ss, off);
    if ((tid & 63) == 0) red[tid >> 6] = ss;
    __syncthreads();
    const float fro = sqrtf(red[0]+red[1]+red[2]+red[3]);
    int s = 0; float scale = 1.0f;
    while (fro * scale > 0.5f && s < 30) { scale *= 0.5f; ++s; }
    x *= scale;

    const float aid = (r == c) ? 1.0f : 0.0f;
    X[tid] = x;
    A[tid] = aid;
    __syncthreads();

    // Horner Taylor-12: A = I + X(I + X/2(I + ... ))
    for (int m = 12; m >= 1; --m) {
        float acc = 0.f;
        #pragma unroll
        for (int k2 = 0; k2 < 16; ++k2) acc += X[r*16+k2] * A[k2*16+c];
        __syncthreads();
        A[tid] = aid + acc / (float)m;
        __syncthreads();
    }
    // square s times
    for (int q = 0; q < s; ++q) {
        float acc = 0.f;
        #pragma unroll
        for (int k2 = 0; k2 < 16; ++k2) acc += A[r*16+k2] * A[k2*16+c];
        __syncthreads();
        A[tid] = acc;
        __syncthreads();
    }

    E_ws[bn*256 + tid] = A[tid];   // row-major E[r][c]

    if (tid < 16) {
        const float sqv = fmaxf(sigma_q[bn*16+tid], EPSV);
        dinv_s[tid] = 1.0f / (sqv + EPSV);
        float vv = 0.f;
        #pragma unroll
        for (int i2 = 0; i2 < 16; ++i2) vv += A[i2*16+tid] * mu_q[bn*16+i2];
        v_ws[bn*16+tid] = vv;      // v = E^T mu
        const float spv = fmaxf(sigma_p[bn*16+tid], EPSV);
        grad_sigma[bn*16+tid] = ALPHA*0.5f*(1.0f/spv - 1.0f/sqv);
    }
    __syncthreads();

    // Minv[r][c] = sum_k E[k][r]*dinv[k]*E[k][c]; store COLUMN-major (c*16+r)
    float acc = 0.f;
    #pragma unroll
    for (int k2 = 0; k2 < 16; ++k2) acc += A[k2*16+r] * dinv_s[k2] * A[k2*16+c];
    Minv_ws[bn*256 + c*16 + r] = acc;
}

__global__ __launch_bounds__(256) void vffn_pairs(
    const float* __restrict__ mu_q, const float* __restrict__ mu_p,
    const float* __restrict__ sigma_p, const float* __restrict__ beta,
    const float* __restrict__ E_ws, const float* __restrict__ Minv_ws,
    const float* __restrict__ v_ws, float* __restrict__ grad_mu)
{
    const int blk = blockIdx.x;            // 0..255
    const int b   = blk >> 5;
    const int i0  = (blk & 31) * TI;
    const int tid = threadIdx.x;
    const int js  = tid >> 4;              // j slot 0..15
    const int k   = tid & 15;              // output row of t

    __shared__ float Ml[16*272];           // 16 Minv mats, stride 272 (bank-friendly)
    __shared__ float vj[16][16];
    __shared__ float vi[TI][16];
    __shared__ float betas[TI][128];
    __shared__ float pa[4][TI][16];
    __shared__ float pc[4][TI][16];
    __shared__ float psd[4][TI];
    __shared__ float gvl[TI][16];

    if (tid < TI*16)
        vi[tid>>4][tid&15] = v_ws[(b*128 + i0 + (tid>>4))*16 + (tid&15)];
    #pragma unroll
    for (int idx = tid; idx < TI*128; idx += 256)
        betas[idx>>7][idx&127] = beta[(b*128 + i0 + (idx>>7))*128 + (idx&127)];

    float acc_a[TI], acc_c[TI], acc_s[TI];
    #pragma unroll
    for (int il = 0; il < TI; ++il) { acc_a[il]=0.f; acc_c[il]=0.f; acc_s[il]=0.f; }

    for (int jc = 0; jc < 8; ++jc) {
        const int jbase = jc * 16;
        __syncthreads();                   // previous chunk's reads complete
        #pragma unroll
        for (int t2 = 0; t2 < 16; ++t2) {  // 16 KB coalesced stage
            const int idx = t2*256 + tid;  // 0..4095
            Ml[(idx>>8)*272 + (idx&255)] = Minv_ws[(b*128 + jbase)*256 + idx];
        }
        vj[tid>>4][tid&15] = v_ws[(b*128 + jbase + (tid>>4))*16 + (tid&15)];
        __syncthreads();

        float mreg[16], wjr[16];
        #pragma unroll
        for (int c2 = 0; c2 < 16; ++c2) mreg[c2] = Ml[js*272 + c2*16 + k]; // col-major row k
        #pragma unroll
        for (int c2 = 0; c2 < 16; ++c2) wjr[c2] = vj[js][c2];

        #pragma unroll
        for (int il = 0; il < TI; ++il) {
            float w[16];
            float t_k = 0.f;
            #pragma unroll
            for (int c2 = 0; c2 < 16; ++c2) {
                w[c2] = vi[il][c2] - wjr[c2];
                t_k += mreg[c2] * w[c2];
            }
            // kl = 0.5 * sum_k w[k]*t[k] across the 16 lanes of this js group
            float pr = w[k] * t_k;
            pr += __shfl_xor(pr, 8, 16);
            pr += __shfl_xor(pr, 4, 16);
            pr += __shfl_xor(pr, 2, 16);
            pr += __shfl_xor(pr, 1, 16);
            const float kl = 0.5f * pr;
            const float ba = betas[il][jbase + js];
            const float bk = ba * kl;
            acc_a[il] += ba * t_k;
            acc_c[il] += bk * t_k;
            acc_s[il] += bk;
        }
    }

    // reduce the 4 js-slots within each wave (stride-16 lanes)
    #pragma unroll
    for (int il = 0; il < TI; ++il) {
        acc_a[il] += __shfl_down(acc_a[il], 32);
        acc_a[il] += __shfl_down(acc_a[il], 16);
        acc_c[il] += __shfl_down(acc_c[il], 32);
        acc_c[il] += __shfl_down(acc_c[il], 16);
        acc_s[il] += __shfl_down(acc_s[il], 32);
        acc_s[il] += __shfl_down(acc_s[il], 16);
    }
    const int wave = tid >> 6, lane = tid & 63;
    if (lane < 16) {
        #pragma unroll
        for (int il = 0; il < TI; ++il) {
            pa[wave][il][k] = acc_a[il];
            pc[wave][il][k] = acc_c[il];
            if (k == 0) psd[wave][il] = acc_s[il];
        }
    }
    __syncthreads();

    if (tid < TI*16) {
        const int il = tid >> 4, kk = tid & 15;
        const float Av = pa[0][il][kk]+pa[1][il][kk]+pa[2][il][kk]+pa[3][il][kk];
        const float Cv = pc[0][il][kk]+pc[1][il][kk]+pc[2][il][kk]+pc[3][il][kk];
        const float Sv = psd[0][il]+psd[1][il]+psd[2][il]+psd[3][il];
        gvl[il][kk] = LAM*Av + (LAM/KAPPA)*(Cv - Sv*Av);
    }
    __syncthreads();

    if (tid < TI*16) {
        const int il = tid >> 4, rr = tid & 15;
        const int gi = b*128 + i0 + il;
        float rot = 0.f;
        #pragma unroll
        for (int k2 = 0; k2 < 16; ++k2)
            rot += E_ws[gi*256 + rr*16 + k2] * gvl[il][k2];
        const int g = gi*16 + rr;
        const float spv = fmaxf(sigma_p[g], EPSV);
        grad_mu[g] = ALPHA*(mu_q[g] - mu_p[g])/spv + rot;
    }
}

extern "C" void kernel_launch(void* const* d_in, const int* in_sizes, int n_in,
                              void* d_out, int out_size, void* d_ws, size_t ws_size,
                              hipStream_t stream) {
    const float* mu_q    = (const float*)d_in[0];
    const float* sigma_q = (const float*)d_in[1];
    const float* mu_p    = (const float*)d_in[2];
    const float* sigma_p = (const float*)d_in[3];
    const float* beta    = (const float*)d_in[4];
    const float* phi     = (const float*)d_in[5];
    const float* gen     = (const float*)d_in[6];

    float* grad_mu    = (float*)d_out;               // 16384
    float* grad_sigma = grad_mu + BB*NN*KK;          // 16384

    float* ws      = (float*)d_ws;
    float* E_ws    = ws;                 // 1024*256
    float* Minv_ws = ws + 262144;        // 1024*256
    float* v_ws    = ws + 524288;        // 1024*16

    vffn_precompute<<<dim3(BB*NN), dim3(256), 0, stream>>>(
        mu_q, sigma_q, sigma_p, phi, gen, E_ws, Minv_ws, v_ws, grad_sigma);
    vffn_pairs<<<dim3(BB*NN/TI), dim3(256), 0, stream>>>(
        mu_q, mu_p, sigma_p, beta, E_ws, Minv_ws, v_ws, grad_mu);
}

// Round 2
// 86.353 us; speedup vs baseline: 1.0564x; 1.0564x over previous
//
#include <hip/hip_runtime.h>

// VariationalFFNGradientEngine — algebraically reduced via orthogonality of
// E = expm(phi . G) (G antisymmetric):
//   v_n    = E_n^T mu_n
//   Minv_n = E_n^T diag(1/(sq_n+eps)) E_n      (exact (Sigma_t+eps I)^{-1} core)
//   t_ij   = Minv_j (v_i - v_j),  kl_ij = 0.5 w.t   (rotated frame)
//   grad_mu_i = self + E_i [ LAM*a + (LAM/KAPPA)(c - s*a) ]
//     a = sum_j beta t, c = sum_j beta*kl*t, s = sum_j beta*kl
//
// R2: precompute uses register-cached X rows + double-buffered A (1 barrier
// per matmul) + deg-9 Horner (first matmul folded). pairs uses
// global_load_lds double-buffered chunk pipeline (1 barrier/chunk).

#define BB 8
#define NN 128
#define KK 16
#define ALPHA 0.01f
#define LAM 1.0f
#define KAPPA 1.0f
#define EPSV 1e-6f
#define TI 4

__global__ __launch_bounds__(256) void vffn_precompute(
    const float* __restrict__ mu_q, const float* __restrict__ sigma_q,
    const float* __restrict__ sigma_p, const float* __restrict__ phi,
    const float* __restrict__ gen,
    float* __restrict__ E_ws, float* __restrict__ Minv_ws,
    float* __restrict__ v_ws, float* __restrict__ grad_sigma)
{
    const int bn  = blockIdx.x;      // 0..1023 = b*128+n
    const int tid = threadIdx.x;     // 0..255 = r*16+c
    const int r = tid >> 4, c = tid & 15;

    __shared__ float X[256];
    __shared__ float A[2][256];
    __shared__ float red[4];
    __shared__ float dinv_s[16];

    const float p0 = phi[bn*3+0], p1 = phi[bn*3+1], p2 = phi[bn*3+2];
    float x = p0*gen[tid] + p1*gen[256+tid] + p2*gen[512+tid];

    // Frobenius norm (bounds spectral norm) for scaling-and-squaring
    float ss = x*x;
    #pragma unroll
    for (int off = 32; off > 0; off >>= 1) ss += __shfl_down(ss, off);
    if ((tid & 63) == 0) red[tid >> 6] = ss;
    __syncthreads();
    const float fro = sqrtf(red[0]+red[1]+red[2]+red[3]);
    int s = 0; float scale = 1.0f;
    while (fro * scale > 0.5f && s < 30) { scale *= 0.5f; ++s; }
    x *= scale;

    const float aid = (r == c) ? 1.0f : 0.0f;
    X[tid] = x;
    A[0][tid] = aid + x * (1.0f/9.0f);   // T = I + X/9 (first Horner step free)
    __syncthreads();

    float xrow[16];                       // X row r — constant across Horner
    #pragma unroll
    for (int j = 0; j < 16; ++j) xrow[j] = X[r*16 + j];

    int cur = 0;
    // Horner deg-9: T = I + X(I + X/2(...)) ; m = 8..1, double-buffered
    #pragma unroll
    for (int m = 8; m >= 1; --m) {
        float acc = 0.f;
        #pragma unroll
        for (int k2 = 0; k2 < 16; ++k2) acc += xrow[k2] * A[cur][k2*16 + c];
        A[1-cur][tid] = aid + acc * (1.0f / (float)m);
        cur ^= 1;
        __syncthreads();
    }
    // square s times (double-buffered, 1 barrier each)
    for (int q = 0; q < s; ++q) {
        float rowr[16];
        #pragma unroll
        for (int j = 0; j < 16; ++j) rowr[j] = A[cur][r*16 + j];
        float acc = 0.f;
        #pragma unroll
        for (int k2 = 0; k2 < 16; ++k2) acc += rowr[k2] * A[cur][k2*16 + c];
        A[1-cur][tid] = acc;
        cur ^= 1;
        __syncthreads();
    }

    E_ws[bn*256 + tid] = A[cur][tid];    // row-major E[r][c]

    if (tid < 16) {
        const float sqv = fmaxf(sigma_q[bn*16+tid], EPSV);
        dinv_s[tid] = 1.0f / (sqv + EPSV);
        float vv = 0.f;
        #pragma unroll
        for (int i2 = 0; i2 < 16; ++i2) vv += A[cur][i2*16+tid] * mu_q[bn*16+i2];
        v_ws[bn*16+tid] = vv;            // v = E^T mu
        const float spv = fmaxf(sigma_p[bn*16+tid], EPSV);
        grad_sigma[bn*16+tid] = ALPHA*0.5f*(1.0f/spv - 1.0f/sqv);
    }
    __syncthreads();

    // Minv[r][c] = sum_k E[k][r]*dinv[k]*E[k][c]; store COLUMN-major (c*16+r)
    float acc = 0.f;
    #pragma unroll
    for (int k2 = 0; k2 < 16; ++k2)
        acc += A[cur][k2*16+r] * dinv_s[k2] * A[cur][k2*16+c];
    Minv_ws[bn*256 + c*16 + r] = acc;
}

#define GLDS16(g, l) __builtin_amdgcn_global_load_lds( \
    (const __attribute__((address_space(1))) unsigned int*)(g), \
    (__attribute__((address_space(3))) unsigned int*)(l), 16, 0, 0)

__global__ __launch_bounds__(256) void vffn_pairs(
    const float* __restrict__ mu_q, const float* __restrict__ mu_p,
    const float* __restrict__ sigma_p, const float* __restrict__ beta,
    const float* __restrict__ E_ws, const float* __restrict__ Minv_ws,
    const float* __restrict__ v_ws, float* __restrict__ grad_mu)
{
    const int blk  = blockIdx.x;           // 0..255
    const int b    = blk >> 5;
    const int i0   = (blk & 31) * TI;
    const int tid  = threadIdx.x;
    const int js   = tid >> 4;             // j slot 0..15
    const int k    = tid & 15;             // output row of t
    const int w    = tid >> 6;             // wave 0..3
    const int lane = tid & 63;

    // double-buffered staged chunk: 16 Minv mats (4096 fl) + 16 v vecs (256 fl)
    __shared__ float Ml[2][4352];
    __shared__ float vi[TI][16];
    __shared__ float betas[TI][128];
    __shared__ float pa[4][TI][16];
    __shared__ float pc[4][TI][16];
    __shared__ float psd[4][TI];
    __shared__ float gvl[TI][16];

    // ---- stage chunk jc into buffer p (async, wave-uniform LDS base) ----
    auto stage = [&](int jc, int p) {
        const float* msrc = Minv_ws + (size_t)(b*128 + jc*16) * 256;
        #pragma unroll
        for (int q = 0; q < 4; ++q) {
            const int seg = (w*4 + q) * 256;
            GLDS16(msrc + seg + lane*4, &Ml[p][seg]);
        }
        if (w == 0)
            GLDS16(v_ws + (b*128 + jc*16)*16 + lane*4, &Ml[p][4096]);
    };

    stage(0, 0);                           // prologue prefetch

    if (tid < TI*16)
        vi[tid>>4][tid&15] = v_ws[(b*128 + i0 + (tid>>4))*16 + (tid&15)];
    #pragma unroll
    for (int idx = tid; idx < TI*128; idx += 256)
        betas[idx>>7][idx&127] = beta[(b*128 + i0 + (idx>>7))*128 + (idx&127)];

    float acc_a[TI], acc_c[TI], acc_s[TI];
    #pragma unroll
    for (int il = 0; il < TI; ++il) { acc_a[il]=0.f; acc_c[il]=0.f; acc_s[il]=0.f; }

    __syncthreads();                       // drains prologue stage + LDS writes

    for (int jc = 0; jc < 8; ++jc) {
        const int p = jc & 1;
        if (jc < 7) stage(jc+1, 1-p);      // prefetch under current compute

        const float* buf = &Ml[p][0];
        float mreg[16], wjr[16];
        #pragma unroll
        for (int c2 = 0; c2 < 16; ++c2) mreg[c2] = buf[js*256 + c2*16 + k];
        #pragma unroll
        for (int c2 = 0; c2 < 16; ++c2) wjr[c2] = buf[4096 + js*16 + c2];

        const int jbase = jc * 16;
        #pragma unroll
        for (int il = 0; il < TI; ++il) {
            float wv[16];
            float t_k = 0.f;
            #pragma unroll
            for (int c2 = 0; c2 < 16; ++c2) {
                wv[c2] = vi[il][c2] - wjr[c2];
                t_k += mreg[c2] * wv[c2];
            }
            // kl = 0.5 * sum_k w[k]*t[k] across the 16 lanes of this js group
            float pr = wv[k] * t_k;
            pr += __shfl_xor(pr, 8, 16);
            pr += __shfl_xor(pr, 4, 16);
            pr += __shfl_xor(pr, 2, 16);
            pr += __shfl_xor(pr, 1, 16);
            const float kl = 0.5f * pr;
            const float ba = betas[il][jbase + js];
            const float bk = ba * kl;
            acc_a[il] += ba * t_k;
            acc_c[il] += bk * t_k;
            acc_s[il] += bk;
        }
        __syncthreads();                   // drains prefetch + buf reads done
    }

    // reduce the 4 js-slots within each wave (stride-16 lanes)
    #pragma unroll
    for (int il = 0; il < TI; ++il) {
        acc_a[il] += __shfl_down(acc_a[il], 32);
        acc_a[il] += __shfl_down(acc_a[il], 16);
        acc_c[il] += __shfl_down(acc_c[il], 32);
        acc_c[il] += __shfl_down(acc_c[il], 16);
        acc_s[il] += __shfl_down(acc_s[il], 32);
        acc_s[il] += __shfl_down(acc_s[il], 16);
    }
    if (lane < 16) {
        #pragma unroll
        for (int il = 0; il < TI; ++il) {
            pa[w][il][k] = acc_a[il];
            pc[w][il][k] = acc_c[il];
            if (k == 0) psd[w][il] = acc_s[il];
        }
    }
    __syncthreads();

    if (tid < TI*16) {
        const int il = tid >> 4, kk = tid & 15;
        const float Av = pa[0][il][kk]+pa[1][il][kk]+pa[2][il][kk]+pa[3][il][kk];
        const float Cv = pc[0][il][kk]+pc[1][il][kk]+pc[2][il][kk]+pc[3][il][kk];
        const float Sv = psd[0][il]+psd[1][il]+psd[2][il]+psd[3][il];
        gvl[il][kk] = LAM*Av + (LAM/KAPPA)*(Cv - Sv*Av);
    }
    __syncthreads();

    if (tid < TI*16) {
        const int il = tid >> 4, rr = tid & 15;
        const int gi = b*128 + i0 + il;
        float rot = 0.f;
        #pragma unroll
        for (int k2 = 0; k2 < 16; ++k2)
            rot += E_ws[gi*256 + rr*16 + k2] * gvl[il][k2];
        const int g = gi*16 + rr;
        const float spv = fmaxf(sigma_p[g], EPSV);
        grad_mu[g] = ALPHA*(mu_q[g] - mu_p[g])/spv + rot;
    }
}

extern "C" void kernel_launch(void* const* d_in, const int* in_sizes, int n_in,
                              void* d_out, int out_size, void* d_ws, size_t ws_size,
                              hipStream_t stream) {
    const float* mu_q    = (const float*)d_in[0];
    const float* sigma_q = (const float*)d_in[1];
    const float* mu_p    = (const float*)d_in[2];
    const float* sigma_p = (const float*)d_in[3];
    const float* beta    = (const float*)d_in[4];
    const float* phi     = (const float*)d_in[5];
    const float* gen     = (const float*)d_in[6];

    float* grad_mu    = (float*)d_out;               // 16384
    float* grad_sigma = grad_mu + BB*NN*KK;          // 16384

    float* ws      = (float*)d_ws;
    float* E_ws    = ws;                 // 1024*256
    float* Minv_ws = ws + 262144;        // 1024*256
    float* v_ws    = ws + 524288;        // 1024*16

    vffn_precompute<<<dim3(BB*NN), dim3(256), 0, stream>>>(
        mu_q, sigma_q, sigma_p, phi, gen, E_ws, Minv_ws, v_ws, grad_sigma);
    vffn_pairs<<<dim3(BB*NN/TI), dim3(256), 0, stream>>>(
        mu_q, mu_p, sigma_p, beta, E_ws, Minv_ws, v_ws, grad_mu);
}

// Round 3
// 82.212 us; speedup vs baseline: 1.1097x; 1.0504x over previous
//
#include <hip/hip_runtime.h>

// VariationalFFNGradientEngine — algebraically reduced via orthogonality of
// E = expm(phi . G) (G antisymmetric):
//   v_n    = E_n^T mu_n
//   Minv_n = E_n^T diag(1/(sq_n+eps)) E_n      (exact (Sigma_t+eps I)^{-1} core)
//   t_ij   = Minv_j (v_i - v_j),  kl_ij = 0.5 w.t   (rotated frame)
//   grad_mu_i = self + E_i [ LAM*a + (LAM/KAPPA)(c - s*a) ]
//     a = sum_j beta t, c = sum_j beta*kl*t, s = sum_j beta*kl
//
// R3: precompute = Paterson-Stockmeyer deg-12 Taylor (5 matmuls + ~4 sq),
// col-major LDS + b128 column reads. pairs = 512 threads (8 waves/CU),
// stride-272 staging (2-way bank alias = free), E_i prefetched to LDS.

#define BB 8
#define NN 128
#define ALPHA 0.01f
#define LAM 1.0f
#define KAPPA 1.0f
#define EPSV 1e-6f
#define TI 4

__device__ __forceinline__ float dot16(const float* row, const float* colbase) {
    const float4* c4 = (const float4*)colbase;   // 64B-aligned LDS column
    float4 a = c4[0], b = c4[1], c = c4[2], d = c4[3];
    return row[0]*a.x + row[1]*a.y + row[2]*a.z + row[3]*a.w
         + row[4]*b.x + row[5]*b.y + row[6]*b.z + row[7]*b.w
         + row[8]*c.x + row[9]*c.y + row[10]*c.z + row[11]*c.w
         + row[12]*d.x + row[13]*d.y + row[14]*d.z + row[15]*d.w;
}

__global__ __launch_bounds__(256) void vffn_precompute(
    const float* __restrict__ mu_q, const float* __restrict__ sigma_q,
    const float* __restrict__ sigma_p, const float* __restrict__ phi,
    const float* __restrict__ gen,
    float* __restrict__ E_ws, float* __restrict__ Minv_ws,
    float* __restrict__ v_ws, float* __restrict__ grad_sigma)
{
    const int bn  = blockIdx.x;      // 0..1023 = b*128+n
    const int tid = threadIdx.x;     // element (row p, col q), tid = q*16+p
    const int p = tid & 15;          // row
    const int q = tid >> 4;          // col

    __shared__ float Xc[256];        // X col-major
    __shared__ float Zc[256];        // Z = X^3 col-major
    __shared__ float T[2][256];      // col-major work buffers
    __shared__ float red[4];
    __shared__ float dinv_s[16];

    const float p0 = phi[bn*3+0], p1 = phi[bn*3+1], p2 = phi[bn*3+2];
    // gen[a*256+tid] = G_a[q][p]; antisymmetry => X[p][q] = -sum_a phi_a G_a[q][p]
    float x = -(p0*gen[tid] + p1*gen[256+tid] + p2*gen[512+tid]);

    // Frobenius norm (bounds spectral) for scaling-and-squaring
    float ss = x*x;
    #pragma unroll
    for (int off = 32; off > 0; off >>= 1) ss += __shfl_down(ss, off);
    if ((tid & 63) == 0) red[tid >> 6] = ss;
    __syncthreads();
    const float fro = sqrtf(red[0]+red[1]+red[2]+red[3]);
    int s = 0; float scale = 1.0f;
    while (fro * scale > 1.0f && s < 30) { scale *= 0.5f; ++s; }
    x *= scale;

    Xc[tid] = x;                     // col-major: index q*16+p == tid
    __syncthreads();

    float rowX[16];
    #pragma unroll
    for (int j = 0; j < 16; ++j) rowX[j] = Xc[j*16 + p];   // conflict-free

    // X2 = X*X  (thread's own element)
    const float x2 = dot16(rowX, &Xc[q*16]);
    T[0][tid] = x2;                  // X2 col-major (temp in T[0])
    __syncthreads();

    // Z = X*X2 = X^3
    const float z = dot16(rowX, &T[0][q*16]);
    Zc[tid] = z;
    __syncthreads();

    float rowZ[16];
    #pragma unroll
    for (int j = 0; j < 16; ++j) rowZ[j] = Zc[j*16 + p];

    const float aid = (p == q) ? 1.0f : 0.0f;
    // Paterson-Stockmeyer deg-12: T = B0 + Z(B1 + Z(B2 + Z(B3 + c12*Z)))
    // B3 = I/9! + X/10! + X2/11!, c12 = 1/12!
    T[0][tid] = 2.7557319e-6f*aid + 2.7557319e-7f*x + 2.5052108e-8f*x2
              + 2.0876757e-9f*z;
    int cur = 0;
    __syncthreads();

    const float bI[3]  = {1.3888889e-3f, 1.6666667e-1f, 1.0f};  // B2,B1,B0: I
    const float bX[3]  = {1.9841270e-4f, 4.1666668e-2f, 1.0f};  //         : X
    const float bX2[3] = {2.4801587e-5f, 8.3333333e-3f, 0.5f};  //         : X2
    #pragma unroll
    for (int h = 0; h < 3; ++h) {
        const float d = dot16(rowZ, &T[cur][q*16]);   // (Z*T)[p][q]
        T[1-cur][tid] = bI[h]*aid + bX[h]*x + bX2[h]*x2 + d;
        cur ^= 1;
        __syncthreads();
    }
    // undo scaling: square s times
    for (int qq = 0; qq < s; ++qq) {
        float rowT[16];
        #pragma unroll
        for (int j = 0; j < 16; ++j) rowT[j] = T[cur][j*16 + p];
        const float d = dot16(rowT, &T[cur][q*16]);
        T[1-cur][tid] = d;
        cur ^= 1;
        __syncthreads();
    }

    // E col-major in T[cur]. Write E row-major to E_ws.
    E_ws[bn*256 + tid] = T[cur][(tid & 15)*16 + (tid >> 4)];

    if (tid < 16) {
        const float sqv = fmaxf(sigma_q[bn*16+tid], EPSV);
        dinv_s[tid] = 1.0f / (sqv + EPSV);
        float vv = 0.f;
        #pragma unroll
        for (int i2 = 0; i2 < 16; ++i2) vv += T[cur][tid*16 + i2] * mu_q[bn*16+i2];
        v_ws[bn*16+tid] = vv;        // v = E^T mu
        const float spv = fmaxf(sigma_p[bn*16+tid], EPSV);
        grad_sigma[bn*16+tid] = ALPHA*0.5f*(1.0f/spv - 1.0f/sqv);
    }
    __syncthreads();

    // Minv[p][q] = sum_k E[k][p]*dinv[k]*E[k][q]; store col-major at tid
    float acc = 0.f;
    #pragma unroll
    for (int k2 = 0; k2 < 16; ++k2)
        acc += T[cur][p*16+k2] * dinv_s[k2] * T[cur][q*16+k2];
    Minv_ws[bn*256 + tid] = acc;
}

#define GLDS16(g, l) __builtin_amdgcn_global_load_lds( \
    (const __attribute__((address_space(1))) unsigned int*)(g), \
    (__attribute__((address_space(3))) unsigned int*)(l), 16, 0, 0)

__global__ __launch_bounds__(512) void vffn_pairs(
    const float* __restrict__ mu_q, const float* __restrict__ mu_p,
    const float* __restrict__ sigma_p, const float* __restrict__ beta,
    const float* __restrict__ E_ws, const float* __restrict__ Minv_ws,
    const float* __restrict__ v_ws, float* __restrict__ grad_mu)
{
    const int blk  = blockIdx.x;           // 0..255
    const int b    = blk >> 5;
    const int i0   = (blk & 31) * TI;
    const int tid  = threadIdx.x;          // 0..511
    const int jsl  = (tid >> 4) & 15;      // j slot 0..15
    const int k    = tid & 15;             // row of t
    const int w    = tid >> 6;             // wave 0..7
    const int lane = tid & 63;
    const int rep  = w >> 2;               // 0: il 0,1 ; 1: il 2,3

    // 16 Minv mats @ stride 272 (2-way alias = free) + 16 v vecs, x2 buffers
    __shared__ float Ml[2][16*272 + 256];  // 4608 floats each
    __shared__ float Ei[TI*256];           // E_i for epilogue rotation
    __shared__ float vi[TI][16];
    __shared__ float betas[TI][128];
    __shared__ float pa[8][2][16];
    __shared__ float pc[8][2][16];
    __shared__ float psd[8][2];
    __shared__ float gvl[TI][16];

    auto stage = [&](int jc, int pb) {
        const float* msrc = Minv_ws + (size_t)(b*128 + jc*16) * 256;
        #pragma unroll
        for (int t2 = 0; t2 < 2; ++t2) {
            const int m = w*2 + t2;                    // wave-uniform
            GLDS16(msrc + m*256 + lane*4, &Ml[pb][m*272]);
        }
        if (w == 0)
            GLDS16(v_ws + (b*128 + jc*16)*16 + lane*4, &Ml[pb][4352]);
    };

    stage(0, 0);                           // prologue prefetch
    if (w == 1) {                          // prefetch E_i (used only at end)
        #pragma unroll
        for (int t2 = 0; t2 < TI; ++t2)
            GLDS16(E_ws + (size_t)(b*128 + i0)*256 + t2*256 + lane*4, &Ei[t2*256]);
    }
    if (tid < TI*16)
        vi[tid>>4][tid&15] = v_ws[(b*128 + i0 + (tid>>4))*16 + (tid&15)];
    betas[tid>>7][tid&127] = beta[(b*128 + i0 + (tid>>7))*128 + (tid&127)];

    float acc_a[2] = {0.f, 0.f}, acc_c[2] = {0.f, 0.f}, acc_s[2] = {0.f, 0.f};

    __syncthreads();                       // drains prologue staging

    for (int jc = 0; jc < 8; ++jc) {
        const int pb = jc & 1;
        if (jc < 7) stage(jc+1, 1-pb);     // prefetch under current compute

        const float* buf = &Ml[pb][0];
        float mreg[16], wjr[16];
        #pragma unroll
        for (int c2 = 0; c2 < 16; ++c2) mreg[c2] = buf[jsl*272 + c2*16 + k];
        #pragma unroll
        for (int c2 = 0; c2 < 16; ++c2) wjr[c2] = buf[4352 + jsl*16 + c2];

        const int jbase = jc * 16;
        #pragma unroll
        for (int il2 = 0; il2 < 2; ++il2) {
            const int il = rep*2 + il2;
            float wv[16];
            float t_k = 0.f;
            #pragma unroll
            for (int c2 = 0; c2 < 16; ++c2) {
                wv[c2] = vi[il][c2] - wjr[c2];
                t_k += mreg[c2] * wv[c2];
            }
            float pr = wv[k] * t_k;        // kl over the 16 lanes of this slot
            pr += __shfl_xor(pr, 8, 16);
            pr += __shfl_xor(pr, 4, 16);
            pr += __shfl_xor(pr, 2, 16);
            pr += __shfl_xor(pr, 1, 16);
            const float kl = 0.5f * pr;
            const float ba = betas[il][jbase + jsl];
            const float bk = ba * kl;
            acc_a[il2] += ba * t_k;
            acc_c[il2] += bk * t_k;
            acc_s[il2] += bk;
        }
        __syncthreads();                   // buf reads done; prefetch drained
    }

    // reduce 4 jsl-slots within each wave (stride-16 lanes)
    #pragma unroll
    for (int il2 = 0; il2 < 2; ++il2) {
        acc_a[il2] += __shfl_down(acc_a[il2], 32);
        acc_a[il2] += __shfl_down(acc_a[il2], 16);
        acc_c[il2] += __shfl_down(acc_c[il2], 32);
        acc_c[il2] += __shfl_down(acc_c[il2], 16);
        acc_s[il2] += __shfl_down(acc_s[il2], 32);
        acc_s[il2] += __shfl_down(acc_s[il2], 16);
    }
    if (lane < 16) {
        #pragma unroll
        for (int il2 = 0; il2 < 2; ++il2) {
            pa[w][il2][k] = acc_a[il2];
            pc[w][il2][k] = acc_c[il2];
            if (k == 0) psd[w][il2] = acc_s[il2];
        }
    }
    __syncthreads();

    if (tid < TI*16) {
        const int il = tid >> 4, kk = tid & 15;
        const int r4 = (il >> 1) * 4, il2 = il & 1;
        float Av = 0.f, Cv = 0.f, Sv = 0.f;
        #pragma unroll
        for (int ww = 0; ww < 4; ++ww) {
            Av += pa[r4+ww][il2][kk];
            Cv += pc[r4+ww][il2][kk];
            Sv += psd[r4+ww][il2];
        }
        gvl[il][kk] = LAM*Av + (LAM/KAPPA)*(Cv - Sv*Av);
    }
    __syncthreads();

    if (tid < TI*16) {
        const int il = tid >> 4, rr = tid & 15;
        const int gi = b*128 + i0 + il;
        float rot = 0.f;
        #pragma unroll
        for (int k2 = 0; k2 < 16; ++k2)
            rot += Ei[il*256 + rr*16 + k2] * gvl[il][k2];
        const int g = gi*16 + rr;
        const float spv = fmaxf(sigma_p[g], EPSV);
        grad_mu[g] = ALPHA*(mu_q[g] - mu_p[g])/spv + rot;
    }
}

extern "C" void kernel_launch(void* const* d_in, const int* in_sizes, int n_in,
                              void* d_out, int out_size, void* d_ws, size_t ws_size,
                              hipStream_t stream) {
    const float* mu_q    = (const float*)d_in[0];
    const float* sigma_q = (const float*)d_in[1];
    const float* mu_p    = (const float*)d_in[2];
    const float* sigma_p = (const float*)d_in[3];
    const float* beta    = (const float*)d_in[4];
    const float* phi     = (const float*)d_in[5];
    const float* gen     = (const float*)d_in[6];

    float* grad_mu    = (float*)d_out;               // 16384
    float* grad_sigma = grad_mu + BB*NN*16;          // 16384

    float* ws      = (float*)d_ws;
    float* E_ws    = ws;                 // 1024*256
    float* Minv_ws = ws + 262144;        // 1024*256
    float* v_ws    = ws + 524288;        // 1024*16

    vffn_precompute<<<dim3(BB*NN), dim3(256), 0, stream>>>(
        mu_q, sigma_q, sigma_p, phi, gen, E_ws, Minv_ws, v_ws, grad_sigma);
    vffn_pairs<<<dim3(BB*NN/TI), dim3(512), 0, stream>>>(
        mu_q, mu_p, sigma_p, beta, E_ws, Minv_ws, v_ws, grad_mu);
}